// Round 1
// baseline (915.920 us; speedup 1.0000x reference)
//
#include <hip/hip_runtime.h>
#include <math.h>

#define D 128
#define MAXD 8
#define PG 16
#define EPSV 1e-5f

__device__ __forceinline__ float sigmoidf_(float x) {
    return 1.0f / (1.0f + __expf(-x));
}
__device__ __forceinline__ float tanhf_(float x) {
    // tanh(x) = 1 - 2/(e^{2x}+1); saturates correctly for large |x|
    return 1.0f - 2.0f / (__expf(2.0f * x) + 1.0f);
}

// ---------------- weight transposes: w[r][c] -> wT[c][r] -----------------
__global__ void prep_kernel(const float* __restrict__ wih, const float* __restrict__ whh,
                            const float* __restrict__ fs,  const float* __restrict__ fn,
                            const float* __restrict__ fu,  const float* __restrict__ fv,
                            const float* __restrict__ fi,
                            float* __restrict__ wiT, float* __restrict__ whT,
                            float* __restrict__ fsT, float* __restrict__ fnT,
                            float* __restrict__ fuT, float* __restrict__ fvT,
                            float* __restrict__ fiT) {
    int i = blockIdx.x * blockDim.x + threadIdx.x;
    if (i < 3 * D * D) {            // 384x128
        int r = i / D, c = i % D;
        wiT[c * (3 * D) + r] = wih[i];
        whT[c * (3 * D) + r] = whh[i];
    }
    if (i < D * D) {                // 128x128
        int r = i / D, c = i % D;
        fsT[c * D + r] = fs[i];
        fnT[c * D + r] = fn[i];
        fuT[c * D + r] = fu[i];
        fvT[c * D + r] = fv[i];
        fiT[c * D + r] = fi[i];
    }
}

// ---------------- BN1 ----------------------------------------------------
__global__ void bn1_kernel(const float* __restrict__ feat,
                           const float* __restrict__ g, const float* __restrict__ b,
                           const float* __restrict__ m, const float* __restrict__ v,
                           float* __restrict__ x, int nd) {
    int i = blockIdx.x * blockDim.x + threadIdx.x;
    if (i >= nd) return;
    int c = i & (D - 1);
    float scale = g[c] * rsqrtf(v[c] + EPSV);
    x[i] = (feat[i] - m[c]) * scale + b[c];
}

// ---------------- mailbox src table --------------------------------------
__global__ void mbinit_kernel(int* __restrict__ mb, int n) {
    int i = blockIdx.x * blockDim.x + threadIdx.x;
    if (i < n) mb[i] = -1;
}
__global__ void scatter_kernel(const int* __restrict__ src, const int* __restrict__ dst,
                               const int* __restrict__ slot, int* __restrict__ mb, int E) {
    int e = blockIdx.x * blockDim.x + threadIdx.x;
    if (e < E) mb[(size_t)dst[e] * MAXD + slot[e]] = src[e];
}

// ---------------- GRU over mailbox ---------------------------------------
// block: 256 threads = 128 cols x 2 node-groups; 32 nodes/block
__global__ __launch_bounds__(256) void gru_kernel(
        const float* __restrict__ x, const int* __restrict__ mb,
        const float* __restrict__ wiT, const float* __restrict__ whT,
        const float* __restrict__ bih, const float* __restrict__ bhh,
        float* __restrict__ hout) {
    __shared__ float M[32][D];
    __shared__ float H[32][D];
    __shared__ int   srcs[32][MAXD];
    __shared__ int   sTmax;

    const int tid = threadIdx.x;
    const int node0 = blockIdx.x * 32;

    srcs[tid >> 3][tid & 7] = mb[(size_t)(node0 + (tid >> 3)) * MAXD + (tid & 7)];
    for (int r = 0; r < 16; ++r) {
        M[0][r * 256 + tid] = 0.0f;
        H[0][r * 256 + tid] = 0.0f;
    }
    __syncthreads();

    if (tid < 64) {
        int last = -1;
        if (tid < 32) {
            for (int t = 0; t < MAXD; ++t)
                if (srcs[tid][t] >= 0) last = t;
        }
        for (int off = 32; off; off >>= 1) last = max(last, __shfl_xor(last, off));
        if (tid == 0) sTmax = last + 1;
    }
    __syncthreads();
    const int Tmax = sTmax;

    const int c = tid & (D - 1);
    const int grp = tid >> 7;  // 0..1, 16 nodes each
    const float bir = bih[c] + bhh[c];
    const float biz = bih[D + c] + bhh[D + c];
    const float bin = bih[2 * D + c];
    const float bhn = bhh[2 * D + c];

    for (int t = 0; t < Tmax; ++t) {
        // gather messages: 32 rows * 32 float4
        for (int r = 0; r < 4; ++r) {
            int j = r * 256 + tid;      // 0..1023
            int n = j >> 5, c4 = j & 31;
            int s = srcs[n][t];
            if (s >= 0)
                ((float4*)M[n])[c4] = ((const float4*)(x + (size_t)s * D))[c4];
        }
        __syncthreads();

        float ar[16], az[16], ain[16], ahn[16];
#pragma unroll
        for (int n = 0; n < 16; ++n) { ar[n] = bir; az[n] = biz; ain[n] = bin; ahn[n] = bhn; }

        for (int k4 = 0; k4 < D / 4; ++k4) {
            const int k = k4 * 4;
            float wir[4], wiz[4], win[4], whr[4], whz[4], whn[4];
#pragma unroll
            for (int q = 0; q < 4; ++q) {
                const float* wi = wiT + (size_t)(k + q) * (3 * D);
                const float* wh = whT + (size_t)(k + q) * (3 * D);
                wir[q] = wi[c]; wiz[q] = wi[D + c]; win[q] = wi[2 * D + c];
                whr[q] = wh[c]; whz[q] = wh[D + c]; whn[q] = wh[2 * D + c];
            }
#pragma unroll
            for (int n = 0; n < 16; ++n) {
                const int nn = grp * 16 + n;
                float4 m4 = *(const float4*)&M[nn][k];
                float4 h4 = *(const float4*)&H[nn][k];
                float mm[4] = {m4.x, m4.y, m4.z, m4.w};
                float hh[4] = {h4.x, h4.y, h4.z, h4.w};
#pragma unroll
                for (int q = 0; q < 4; ++q) {
                    ar[n]  = fmaf(wir[q], mm[q], fmaf(whr[q], hh[q], ar[n]));
                    az[n]  = fmaf(wiz[q], mm[q], fmaf(whz[q], hh[q], az[n]));
                    ain[n] = fmaf(win[q], mm[q], ain[n]);
                    ahn[n] = fmaf(whn[q], hh[q], ahn[n]);
                }
            }
        }
        __syncthreads();   // all H reads done before updates

#pragma unroll
        for (int n = 0; n < 16; ++n) {
            const int nn = grp * 16 + n;
            if (srcs[nn][t] >= 0) {
                float r = sigmoidf_(ar[n]);
                float z = sigmoidf_(az[n]);
                float nv = tanhf_(ain[n] + r * ahn[n]);
                H[nn][c] = (1.0f - z) * nv + z * H[nn][c];
            }
        }
        __syncthreads();
    }

    for (int r = 0; r < 16; ++r) {
        int j = r * 256 + tid;
        hout[(size_t)node0 * D + j] = H[0][j];
    }
}

// ---------------- rst = x@fc_self^T + h@fc_neigh^T ; PReLU ; BN2 ; in-place f
// block: 256 threads = 64 lanes x 4 node-groups; each thread 2 cols; 32 nodes/block
__global__ __launch_bounds__(256) void rstf_kernel(
        float* __restrict__ x, const float* __restrict__ h,
        const float* __restrict__ fsT, const float* __restrict__ fnT,
        const float* __restrict__ pa,
        const float* __restrict__ bg, const float* __restrict__ bb,
        const float* __restrict__ bm, const float* __restrict__ bv) {
    __shared__ float X[32][D];
    __shared__ float Hh[32][D];
    const int tid = threadIdx.x;
    const size_t base = (size_t)blockIdx.x * 32 * D;

    for (int r = 0; r < 4; ++r) {
        int j = r * 256 + tid;
        ((float4*)X[0])[j]  = ((const float4*)(x + base))[j];
        ((float4*)Hh[0])[j] = ((const float4*)(h + base))[j];
    }
    __syncthreads();

    const int c0 = tid & 63;
    const int c1 = c0 + 64;
    const int grp = tid >> 6;   // 0..3, 8 nodes each
    float acc0[8], acc1[8];
#pragma unroll
    for (int n = 0; n < 8; ++n) { acc0[n] = 0.0f; acc1[n] = 0.0f; }

    for (int k4 = 0; k4 < D / 4; ++k4) {
        const int k = k4 * 4;
        float ws0[4], ws1[4], wn0[4], wn1[4];
#pragma unroll
        for (int q = 0; q < 4; ++q) {
            ws0[q] = fsT[(size_t)(k + q) * D + c0];
            ws1[q] = fsT[(size_t)(k + q) * D + c1];
            wn0[q] = fnT[(size_t)(k + q) * D + c0];
            wn1[q] = fnT[(size_t)(k + q) * D + c1];
        }
#pragma unroll
        for (int n = 0; n < 8; ++n) {
            const int nn = grp * 8 + n;
            float4 m4 = *(const float4*)&X[nn][k];
            float4 h4 = *(const float4*)&Hh[nn][k];
            float mm[4] = {m4.x, m4.y, m4.z, m4.w};
            float hh[4] = {h4.x, h4.y, h4.z, h4.w};
#pragma unroll
            for (int q = 0; q < 4; ++q) {
                acc0[n] = fmaf(ws0[q], mm[q], fmaf(wn0[q], hh[q], acc0[n]));
                acc1[n] = fmaf(ws1[q], mm[q], fmaf(wn1[q], hh[q], acc1[n]));
            }
        }
    }

    const float a0 = pa[c0], a1 = pa[c1];
    const float sc0 = bg[c0] * rsqrtf(bv[c0] + EPSV);
    const float sc1 = bg[c1] * rsqrtf(bv[c1] + EPSV);
    const float sh0 = bb[c0] - bm[c0] * sc0;
    const float sh1 = bb[c1] - bm[c1] * sc1;
#pragma unroll
    for (int n = 0; n < 8; ++n) {
        const int nn = grp * 8 + n;
        float r0 = acc0[n]; r0 = r0 > 0.0f ? r0 : a0 * r0;
        float r1 = acc1[n]; r1 = r1 > 0.0f ? r1 : a1 * r1;
        x[base + (size_t)nn * D + c0] = r0 * sc0 + sh0;
        x[base + (size_t)nn * D + c1] = r1 * sc1 + sh1;
    }
}

// ---------------- per-graph feat_v + feat_l -------------------------------
__global__ __launch_bounds__(256) void vl_kernel(
        const float* __restrict__ intend, const float* __restrict__ f,
        const int* __restrict__ last_nodes,
        const float* __restrict__ fvT, const float* __restrict__ fiT,
        const float* __restrict__ fvb, const float* __restrict__ fib,
        float* __restrict__ out) {
    __shared__ float I[32][D];
    __shared__ float L[32][D];
    const int tid = threadIdx.x;
    const int g0 = blockIdx.x * 32;

    for (int r = 0; r < 4; ++r) {
        int j = r * 256 + tid;
        int n = j >> 5, c4 = j & 31;
        ((float4*)I[n])[c4] = ((const float4*)(intend + (size_t)(g0 + n) * D))[c4];
        int ln = last_nodes[g0 + n];
        ((float4*)L[n])[c4] = ((const float4*)(f + (size_t)ln * D))[c4];
    }
    __syncthreads();

    const int c0 = tid & 63;
    const int c1 = c0 + 64;
    const int grp = tid >> 6;
    float acc0[8], acc1[8];
#pragma unroll
    for (int n = 0; n < 8; ++n) { acc0[n] = 0.0f; acc1[n] = 0.0f; }

    for (int k4 = 0; k4 < D / 4; ++k4) {
        const int k = k4 * 4;
        float wv0[4], wv1[4], wi0[4], wi1[4];
#pragma unroll
        for (int q = 0; q < 4; ++q) {
            wv0[q] = fvT[(size_t)(k + q) * D + c0];
            wv1[q] = fvT[(size_t)(k + q) * D + c1];
            wi0[q] = fiT[(size_t)(k + q) * D + c0];
            wi1[q] = fiT[(size_t)(k + q) * D + c1];
        }
#pragma unroll
        for (int n = 0; n < 8; ++n) {
            const int nn = grp * 8 + n;
            float4 i4 = *(const float4*)&I[nn][k];
            float4 l4 = *(const float4*)&L[nn][k];
            float ii[4] = {i4.x, i4.y, i4.z, i4.w};
            float ll[4] = {l4.x, l4.y, l4.z, l4.w};
#pragma unroll
            for (int q = 0; q < 4; ++q) {
                acc0[n] = fmaf(wv0[q], ii[q], fmaf(wi0[q], ll[q], acc0[n]));
                acc1[n] = fmaf(wv1[q], ii[q], fmaf(wi1[q], ll[q], acc1[n]));
            }
        }
    }
    const float b0 = fvb[c0] + fib[c0];
    const float b1 = fvb[c1] + fib[c1];
#pragma unroll
    for (int n = 0; n < 8; ++n) {
        const int nn = grp * 8 + n;
        out[(size_t)(g0 + nn) * D + c0] = acc0[n] + b0;
        out[(size_t)(g0 + nn) * D + c1] = acc1[n] + b1;
    }
}

// ---------------- attention + readout, one block per graph ---------------
__global__ __launch_bounds__(256) void attn_kernel(
        const float* __restrict__ f, const float* __restrict__ vl,
        const float* __restrict__ fuT, const float* __restrict__ few,
        const float* __restrict__ pw, float* __restrict__ out, int Bn) {
    __shared__ float F[PG][D];
    __shared__ float svl[D];
    __shared__ float epart[4][8];
    __shared__ float alpha[PG];
    __shared__ float spw[PG];
    __shared__ float rpart[2][D];
    __shared__ float ppart[2][D];

    const int g = blockIdx.x;
    const int tid = threadIdx.x;
    const size_t base = (size_t)g * PG * D;

    for (int r = 0; r < 2; ++r) {
        int j = r * 256 + tid;   // 0..511 float4
        ((float4*)F[0])[j] = ((const float4*)(f + base))[j];
    }
    if (tid < D) svl[tid] = vl[(size_t)g * D + tid];
    if (tid < PG) spw[tid] = pw[g * PG + tid];
    __syncthreads();

    const int c = tid & (D - 1);
    const int grp = tid >> 7;  // 0..1, 8 nodes each
    float acc[8];
#pragma unroll
    for (int n = 0; n < 8; ++n) acc[n] = 0.0f;

    for (int k4 = 0; k4 < D / 4; ++k4) {
        const int k = k4 * 4;
        float wu[4];
#pragma unroll
        for (int q = 0; q < 4; ++q) wu[q] = fuT[(size_t)(k + q) * D + c];
#pragma unroll
        for (int n = 0; n < 8; ++n) {
            float4 f4 = *(const float4*)&F[grp * 8 + n][k];
            float ff[4] = {f4.x, f4.y, f4.z, f4.w};
#pragma unroll
            for (int q = 0; q < 4; ++q) acc[n] = fmaf(wu[q], ff[q], acc[n]);
        }
    }

    const float fe = few[c];
    const float vlc = svl[c];
    float p[8];
#pragma unroll
    for (int n = 0; n < 8; ++n) p[n] = sigmoidf_(acc[n] + vlc) * fe;
#pragma unroll
    for (int n = 0; n < 8; ++n)
        for (int off = 32; off; off >>= 1) p[n] += __shfl_xor(p[n], off);
    const int wave = tid >> 6;
    if ((tid & 63) == 0) {
#pragma unroll
        for (int n = 0; n < 8; ++n) epart[wave][n] = p[n];
    }
    __syncthreads();

    if (tid < PG) {
        const int gg = tid >> 3, n = tid & 7;
        float e = epart[gg * 2][n] + epart[gg * 2 + 1][n];
        float mx = e;
#pragma unroll
        for (int off = 8; off; off >>= 1) mx = fmaxf(mx, __shfl_xor(mx, off, 16));
        float ex = __expf(e - mx);
        float s = ex;
#pragma unroll
        for (int off = 8; off; off >>= 1) s += __shfl_xor(s, off, 16);
        alpha[tid] = ex / s;
    }
    __syncthreads();

    float ra = 0.0f, pacc = 0.0f;
#pragma unroll
    for (int n = 0; n < 8; ++n) {
        const int node = grp * 8 + n;
        float fv = F[node][c];
        ra   = fmaf(alpha[node], fv, ra);
        pacc = fmaf(spw[node],  fv, pacc);
    }
    rpart[grp][c] = ra;
    ppart[grp][c] = pacc;
    __syncthreads();
    if (grp == 0) {
        out[(size_t)g * D + c] = rpart[0][c] + rpart[1][c];
        out[(size_t)Bn * D + (size_t)g * D + c] = ppart[0][c] + ppart[1][c];
    }
}

// -------------------------------------------------------------------------
extern "C" void kernel_launch(void* const* d_in, const int* in_sizes, int n_in,
                              void* d_out, int out_size, void* d_ws, size_t ws_size,
                              hipStream_t stream) {
    const float* feat   = (const float*)d_in[0];
    const float* intend = (const float*)d_in[1];
    const float* posw   = (const float*)d_in[2];
    const float* bn1g   = (const float*)d_in[3];
    const float* bn1b   = (const float*)d_in[4];
    const float* bn1m   = (const float*)d_in[5];
    const float* bn1v   = (const float*)d_in[6];
    const float* gwih   = (const float*)d_in[7];
    const float* gwhh   = (const float*)d_in[8];
    const float* gbih   = (const float*)d_in[9];
    const float* gbhh   = (const float*)d_in[10];
    const float* fcs    = (const float*)d_in[11];
    const float* fcn    = (const float*)d_in[12];
    const float* prelu  = (const float*)d_in[13];
    const float* bn2g   = (const float*)d_in[14];
    const float* bn2b   = (const float*)d_in[15];
    const float* bn2m   = (const float*)d_in[16];
    const float* bn2v   = (const float*)d_in[17];
    const float* fcu    = (const float*)d_in[18];
    const float* fcv    = (const float*)d_in[19];
    const float* fcvb   = (const float*)d_in[20];
    const float* fci    = (const float*)d_in[21];
    const float* fcib   = (const float*)d_in[22];
    const float* fce    = (const float*)d_in[23];
    const int* last_nodes = (const int*)d_in[24];
    const int* esrc     = (const int*)d_in[25];
    const int* edst     = (const int*)d_in[26];
    const int* eslot    = (const int*)d_in[27];
    // d_in[28] seg_ids: implied by contiguous PG-node graphs

    const int N = in_sizes[0] / D;
    const int B = in_sizes[1] / D;
    const int E = in_sizes[25];

    float* ws  = (float*)d_ws;
    float* x   = ws;                       // N*D (later holds f in-place)
    float* h   = x + (size_t)N * D;        // N*D
    float* wiT = h + (size_t)N * D;        // 128*384
    float* whT = wiT + 3 * D * D;
    float* fsT = whT + 3 * D * D;          // 128*128 each below
    float* fnT = fsT + D * D;
    float* fuT = fnT + D * D;
    float* fvT = fuT + D * D;
    float* fiT = fvT + D * D;
    float* vlb = fiT + D * D;              // B*D
    int*   mb  = (int*)(vlb + (size_t)B * D);  // N*MAXD

    prep_kernel<<<(3 * D * D + 255) / 256, 256, 0, stream>>>(
        gwih, gwhh, fcs, fcn, fcu, fcv, fci, wiT, whT, fsT, fnT, fuT, fvT, fiT);
    bn1_kernel<<<(N * D + 255) / 256, 256, 0, stream>>>(
        feat, bn1g, bn1b, bn1m, bn1v, x, N * D);
    mbinit_kernel<<<(N * MAXD + 255) / 256, 256, 0, stream>>>(mb, N * MAXD);
    scatter_kernel<<<(E + 255) / 256, 256, 0, stream>>>(esrc, edst, eslot, mb, E);
    gru_kernel<<<N / 32, 256, 0, stream>>>(x, mb, wiT, whT, gbih, gbhh, h);
    rstf_kernel<<<N / 32, 256, 0, stream>>>(x, h, fsT, fnT, prelu, bn2g, bn2b, bn2m, bn2v);
    vl_kernel<<<B / 32, 256, 0, stream>>>(intend, x, last_nodes, fvT, fiT, fcvb, fcib, vlb);
    attn_kernel<<<B, 256, 0, stream>>>(x, vlb, fuT, fce, posw, (float*)d_out, B);
}

// Round 2
// 206.747 us; speedup vs baseline: 4.4301x; 4.4301x over previous
//
#include <hip/hip_runtime.h>
#include <math.h>

#define D 128
#define MAXD 8
#define PG 16
#define EPSV 1e-5f

typedef __attribute__((ext_vector_type(8))) short short8;
typedef __attribute__((ext_vector_type(4))) float f32x4;

__device__ __forceinline__ float sigmoidf_(float x) {
    return 1.0f / (1.0f + __expf(-x));
}
__device__ __forceinline__ float tanhf_(float x) {
    return 1.0f - 2.0f / (__expf(2.0f * x) + 1.0f);
}
__device__ __forceinline__ unsigned short f2bf(float f) {
    unsigned int b = __float_as_uint(f);
    b += 0x7FFFu + ((b >> 16) & 1u);
    return (unsigned short)(b >> 16);
}
__device__ __forceinline__ float bf2f(unsigned short u) {
    return __uint_as_float(((unsigned int)u) << 16);
}

// ---------------- prep: bf16 weight images + f32 transposes + bn1 affine ----
__global__ void prep_kernel(const float* __restrict__ wih, const float* __restrict__ whh,
                            const float* __restrict__ fs,  const float* __restrict__ fn,
                            const float* __restrict__ fu,  const float* __restrict__ fv,
                            const float* __restrict__ fi,
                            const float* __restrict__ g1, const float* __restrict__ b1,
                            const float* __restrict__ m1, const float* __restrict__ v1,
                            unsigned short* __restrict__ wih_bf, unsigned short* __restrict__ whh_bf,
                            unsigned short* __restrict__ fcs_bf, unsigned short* __restrict__ fcn_bf,
                            float* __restrict__ fuT, float* __restrict__ fvT, float* __restrict__ fiT,
                            float* __restrict__ bn1sc, float* __restrict__ bn1sh) {
    int i = blockIdx.x * blockDim.x + threadIdx.x;
    if (i < 3 * D * D) {
        wih_bf[i] = f2bf(wih[i]);
        whh_bf[i] = f2bf(whh[i]);
    }
    if (i < D * D) {
        fcs_bf[i] = f2bf(fs[i]);
        fcn_bf[i] = f2bf(fn[i]);
        int r = i / D, c = i % D;
        fuT[c * D + r] = fu[i];
        fvT[c * D + r] = fv[i];
        fiT[c * D + r] = fi[i];
    }
    if (i < D) {
        float sc = g1[i] * rsqrtf(v1[i] + EPSV);
        bn1sc[i] = sc;
        bn1sh[i] = b1[i] - m1[i] * sc;
    }
}

// ---------------- BN1 -> swizzled bf16 x image ----------------------------
// thread j: row = j>>4, unit u = j&15 (8 bf16 cols = 16B)
__global__ void bn1_kernel(const float* __restrict__ feat,
                           const float* __restrict__ sc, const float* __restrict__ sh,
                           char* __restrict__ x_img, int nunits) {
    int j = blockIdx.x * blockDim.x + threadIdx.x;
    if (j >= nunits) return;
    int row = j >> 4, u = j & 15;
    const float4* fp = (const float4*)(feat + (size_t)row * D + u * 8);
    const float4* sp = (const float4*)(sc + u * 8);
    const float4* hp = (const float4*)(sh + u * 8);
    float4 f0 = fp[0], f1 = fp[1];
    float4 s0 = sp[0], s1 = sp[1];
    float4 h0 = hp[0], h1 = hp[1];
    unsigned int w[4];
    w[0] = (unsigned int)f2bf(f0.x * s0.x + h0.x) | ((unsigned int)f2bf(f0.y * s0.y + h0.y) << 16);
    w[1] = (unsigned int)f2bf(f0.z * s0.z + h0.z) | ((unsigned int)f2bf(f0.w * s0.w + h0.w) << 16);
    w[2] = (unsigned int)f2bf(f1.x * s1.x + h1.x) | ((unsigned int)f2bf(f1.y * s1.y + h1.y) << 16);
    w[3] = (unsigned int)f2bf(f1.z * s1.z + h1.z) | ((unsigned int)f2bf(f1.w * s1.w + h1.w) << 16);
    uint4* dst = (uint4*)(x_img + (size_t)row * 256 + (size_t)((u ^ (row & 7)) << 4));
    *dst = make_uint4(w[0], w[1], w[2], w[3]);
}

// ---------------- mailbox src table --------------------------------------
__global__ void mbinit_kernel(int* __restrict__ mb, int n) {
    int i = blockIdx.x * blockDim.x + threadIdx.x;
    if (i < n) mb[i] = -1;
}
__global__ void scatter_kernel(const int* __restrict__ src, const int* __restrict__ dst,
                               const int* __restrict__ slot, int* __restrict__ mb, int E) {
    int e = blockIdx.x * blockDim.x + threadIdx.x;
    if (e < E) mb[(size_t)dst[e] * MAXD + slot[e]] = src[e];
}

// ---------------- fused EOPA: xg GEMM + GRU t-loop + rst/PReLU/BN2 --------
// 512 threads = 8 waves; block = 128 nodes (8 graphs). Wave w owns output
// cols w*16..w*16+15 (all three gates). MFMA 16x16x32 bf16.
__global__ __launch_bounds__(512, 2) void gru_fused_kernel(
        const char* __restrict__ x_img, const int* __restrict__ mb,
        const unsigned short* __restrict__ wih_bf, const unsigned short* __restrict__ whh_bf,
        const float* __restrict__ gbih, const float* __restrict__ gbhh,
        const unsigned short* __restrict__ fcs_bf, const unsigned short* __restrict__ fcn_bf,
        const float* __restrict__ prelu,
        const float* __restrict__ bg, const float* __restrict__ bb,
        const float* __restrict__ bm, const float* __restrict__ bv,
        float* __restrict__ fout) {
    __shared__ __align__(16) char sXG[128 * 768];   // xg bf16, swizzled
    __shared__ __align__(16) char sXH[128 * 256];   // x then H, bf16, swizzled
    __shared__ int sSrc[128][9];
    __shared__ int sDeg[128];
    __shared__ int sTmax;

    const int tid = threadIdx.x;
    const int w = tid >> 6;          // wave 0..7
    const int lane = tid & 63;
    const int lc = lane & 15;        // col-in-frag
    const int lg = lane >> 4;        // 0..3
    const int c0 = w * 16;
    const int c = c0 + lc;           // this lane's output column 0..127
    const int node0 = blockIdx.x * 128;

    // ---- stage x tile + srcs ----
    {
        const uint4* xs = (const uint4*)(x_img + (size_t)node0 * 256);
        uint4* xd = (uint4*)sXH;
#pragma unroll
        for (int r = 0; r < 4; ++r) xd[r * 512 + tid] = xs[r * 512 + tid];
#pragma unroll
        for (int r = 0; r < 2; ++r) {
            int j = r * 512 + tid;
            int rr = j >> 3, ss = j & 7;
            int s = mb[(size_t)(node0 + rr) * MAXD + ss];
            sSrc[rr][ss] = (s >= 0) ? (s - node0) : -1;
        }
    }
    __syncthreads();
    if (tid < 128) {
        int d = 0;
        while (d < MAXD && sSrc[tid][d] >= 0) ++d;
        sDeg[tid] = d;
    }
    __syncthreads();
    if (tid < 64) {
        int m = max(sDeg[tid], sDeg[tid + 64]);
        for (int off = 32; off; off >>= 1) m = max(m, __shfl_xor(m, off));
        if (tid == 0) sTmax = m;
    }

    // ---- phase B: xg = x @ w_ih^T + b_ih -> sXG ----
    {
        short8 bW[3][4];
#pragma unroll
        for (int g = 0; g < 3; ++g)
#pragma unroll
            for (int kf = 0; kf < 4; ++kf)
                bW[g][kf] = *(const short8*)(wih_bf + (size_t)(g * D + c) * D + kf * 32 + lg * 8);

        __syncthreads();   // sTmax written; sXH staged (covered by earlier syncs)
        const int Tmax0 = sTmax;

        f32x4 acc[8][3];
#pragma unroll
        for (int i = 0; i < 8; ++i) {
            short8 aF[4];
#pragma unroll
            for (int kf = 0; kf < 4; ++kf) {
                int row = i * 16 + lc;
                int u = kf * 4 + lg;
                aF[kf] = *(const short8*)(sXH + row * 256 + ((u ^ (row & 7)) << 4));
            }
#pragma unroll
            for (int g = 0; g < 3; ++g) {
                f32x4 a = {0.f, 0.f, 0.f, 0.f};
#pragma unroll
                for (int kf = 0; kf < 4; ++kf)
                    a = __builtin_amdgcn_mfma_f32_16x16x32_bf16(aF[kf], bW[g][kf], a, 0, 0, 0);
                acc[i][g] = a;
            }
        }
        float bi0 = gbih[c], bi1 = gbih[D + c], bi2 = gbih[2 * D + c];
#pragma unroll
        for (int i = 0; i < 8; ++i) {
#pragma unroll
            for (int p = 0; p < 4; ++p) {
                int row = i * 16 + lg * 4 + p;
#pragma unroll
                for (int g = 0; g < 3; ++g) {
                    int colx = g * D + c;
                    float v = acc[i][g][p] + (g == 0 ? bi0 : (g == 1 ? bi1 : bi2));
                    *(unsigned short*)(sXG + row * 768 + (((colx >> 3) ^ (row & 7)) << 4)
                                       + (colx & 7) * 2) = f2bf(v);
                }
            }
        }
        (void)Tmax0;
    }
    __syncthreads();   // XG visible; x-reads of sXH done -> safe to overwrite as H

    // ---- phase C: GRU t-loop ----
    int Tmax = sTmax;
    if (Tmax < 1) Tmax = 1;

    short8 bH[3][4];
#pragma unroll
    for (int g = 0; g < 3; ++g)
#pragma unroll
        for (int kf = 0; kf < 4; ++kf)
            bH[g][kf] = *(const short8*)(whh_bf + (size_t)(g * D + c) * D + kf * 32 + lg * 8);

    const float bhr = gbhh[c], bhz = gbhh[D + c], bhn = gbhh[2 * D + c];
    float hreg[8][4];
#pragma unroll
    for (int i = 0; i < 8; ++i)
#pragma unroll
        for (int p = 0; p < 4; ++p) hreg[i][p] = 0.0f;

    for (int t = 0; t < Tmax; ++t) {
        f32x4 acc[8][3];
        if (t > 0) {
#pragma unroll
            for (int i = 0; i < 8; ++i) {
                short8 aF[4];
#pragma unroll
                for (int kf = 0; kf < 4; ++kf) {
                    int row = i * 16 + lc;
                    int u = kf * 4 + lg;
                    aF[kf] = *(const short8*)(sXH + row * 256 + ((u ^ (row & 7)) << 4));
                }
#pragma unroll
                for (int g = 0; g < 3; ++g) {
                    f32x4 a = {0.f, 0.f, 0.f, 0.f};
#pragma unroll
                    for (int kf = 0; kf < 4; ++kf)
                        a = __builtin_amdgcn_mfma_f32_16x16x32_bf16(aF[kf], bH[g][kf], a, 0, 0, 0);
                    acc[i][g] = a;
                }
            }
        } else {
#pragma unroll
            for (int i = 0; i < 8; ++i)
#pragma unroll
                for (int g = 0; g < 3; ++g)
                    acc[i][g] = (f32x4){0.f, 0.f, 0.f, 0.f};
        }
        __syncthreads();   // all H reads done before any H write

#pragma unroll
        for (int i = 0; i < 8; ++i) {
#pragma unroll
            for (int p = 0; p < 4; ++p) {
                int row = i * 16 + lg * 4 + p;
                int s = sSrc[row][t];
                int act = s >= 0;
                int s2 = act ? s : 0;
                int b0 = 0 * D + c, b1 = 1 * D + c, b2 = 2 * D + c;
                float gir = bf2f(*(const unsigned short*)(sXG + s2 * 768 +
                                (((b0 >> 3) ^ (s2 & 7)) << 4) + (b0 & 7) * 2));
                float giz = bf2f(*(const unsigned short*)(sXG + s2 * 768 +
                                (((b1 >> 3) ^ (s2 & 7)) << 4) + (b1 & 7) * 2));
                float gin = bf2f(*(const unsigned short*)(sXG + s2 * 768 +
                                (((b2 >> 3) ^ (s2 & 7)) << 4) + (b2 & 7) * 2));
                float r = sigmoidf_(gir + acc[i][0][p] + bhr);
                float z = sigmoidf_(giz + acc[i][1][p] + bhz);
                float n = tanhf_(gin + r * (acc[i][2][p] + bhn));
                float hn = (1.0f - z) * n + z * hreg[i][p];
                hreg[i][p] = act ? hn : hreg[i][p];
                *(unsigned short*)(sXH + row * 256 + (((c >> 3) ^ (row & 7)) << 4)
                                   + (c & 7) * 2) = f2bf(hreg[i][p]);
            }
        }
        __syncthreads();   // H writes visible for next step / phase D
    }

    // ---- phase D: rst = x@fc_self^T + H@fc_neigh^T ; PReLU ; BN2 -> f ----
    short8 bS[4], bN_[4];
#pragma unroll
    for (int kf = 0; kf < 4; ++kf) {
        bS[kf]  = *(const short8*)(fcs_bf + (size_t)c * D + kf * 32 + lg * 8);
        bN_[kf] = *(const short8*)(fcn_bf + (size_t)c * D + kf * 32 + lg * 8);
    }
    const float pa  = prelu[c];
    const float sc2 = bg[c] * rsqrtf(bv[c] + EPSV);
    const float sh2 = bb[c] - bm[c] * sc2;

#pragma unroll
    for (int i = 0; i < 8; ++i) {
        short8 xA[4], hA[4];
#pragma unroll
        for (int kf = 0; kf < 4; ++kf) {
            int row = i * 16 + lc;
            int u = kf * 4 + lg;
            xA[kf] = *(const short8*)(x_img + (size_t)(node0 + row) * 256 + ((u ^ (row & 7)) << 4));
            hA[kf] = *(const short8*)(sXH + row * 256 + ((u ^ (row & 7)) << 4));
        }
        f32x4 a = {0.f, 0.f, 0.f, 0.f};
#pragma unroll
        for (int kf = 0; kf < 4; ++kf)
            a = __builtin_amdgcn_mfma_f32_16x16x32_bf16(xA[kf], bS[kf], a, 0, 0, 0);
#pragma unroll
        for (int kf = 0; kf < 4; ++kf)
            a = __builtin_amdgcn_mfma_f32_16x16x32_bf16(hA[kf], bN_[kf], a, 0, 0, 0);
#pragma unroll
        for (int p = 0; p < 4; ++p) {
            int row = i * 16 + lg * 4 + p;
            float v = a[p];
            v = v > 0.0f ? v : pa * v;
            fout[(size_t)(node0 + row) * D + c] = v * sc2 + sh2;
        }
    }
}

// ---------------- per-graph feat_v + feat_l -------------------------------
__global__ __launch_bounds__(256) void vl_kernel(
        const float* __restrict__ intend, const float* __restrict__ f,
        const int* __restrict__ last_nodes,
        const float* __restrict__ fvT, const float* __restrict__ fiT,
        const float* __restrict__ fvb, const float* __restrict__ fib,
        float* __restrict__ out) {
    __shared__ float I[32][D];
    __shared__ float L[32][D];
    const int tid = threadIdx.x;
    const int g0 = blockIdx.x * 32;

    for (int r = 0; r < 4; ++r) {
        int j = r * 256 + tid;
        int n = j >> 5, c4 = j & 31;
        ((float4*)I[n])[c4] = ((const float4*)(intend + (size_t)(g0 + n) * D))[c4];
        int ln = last_nodes[g0 + n];
        ((float4*)L[n])[c4] = ((const float4*)(f + (size_t)ln * D))[c4];
    }
    __syncthreads();

    const int c0 = tid & 63;
    const int c1 = c0 + 64;
    const int grp = tid >> 6;
    float acc0[8], acc1[8];
#pragma unroll
    for (int n = 0; n < 8; ++n) { acc0[n] = 0.0f; acc1[n] = 0.0f; }

    for (int k4 = 0; k4 < D / 4; ++k4) {
        const int k = k4 * 4;
        float wv0[4], wv1[4], wi0[4], wi1[4];
#pragma unroll
        for (int q = 0; q < 4; ++q) {
            wv0[q] = fvT[(size_t)(k + q) * D + c0];
            wv1[q] = fvT[(size_t)(k + q) * D + c1];
            wi0[q] = fiT[(size_t)(k + q) * D + c0];
            wi1[q] = fiT[(size_t)(k + q) * D + c1];
        }
#pragma unroll
        for (int n = 0; n < 8; ++n) {
            const int nn = grp * 8 + n;
            float4 i4 = *(const float4*)&I[nn][k];
            float4 l4 = *(const float4*)&L[nn][k];
            float ii[4] = {i4.x, i4.y, i4.z, i4.w};
            float ll[4] = {l4.x, l4.y, l4.z, l4.w};
#pragma unroll
            for (int q = 0; q < 4; ++q) {
                acc0[n] = fmaf(wv0[q], ii[q], fmaf(wi0[q], ll[q], acc0[n]));
                acc1[n] = fmaf(wv1[q], ii[q], fmaf(wi1[q], ll[q], acc1[n]));
            }
        }
    }
    const float b0 = fvb[c0] + fib[c0];
    const float b1 = fvb[c1] + fib[c1];
#pragma unroll
    for (int n = 0; n < 8; ++n) {
        const int nn = grp * 8 + n;
        out[(size_t)(g0 + nn) * D + c0] = acc0[n] + b0;
        out[(size_t)(g0 + nn) * D + c1] = acc1[n] + b1;
    }
}

// ---------------- attention + readout, one block per graph ---------------
__global__ __launch_bounds__(256) void attn_kernel(
        const float* __restrict__ f, const float* __restrict__ vl,
        const float* __restrict__ fuT, const float* __restrict__ few,
        const float* __restrict__ pw, float* __restrict__ out, int Bn) {
    __shared__ float F[PG][D];
    __shared__ float svl[D];
    __shared__ float epart[4][8];
    __shared__ float alpha[PG];
    __shared__ float spw[PG];
    __shared__ float rpart[2][D];
    __shared__ float ppart[2][D];

    const int g = blockIdx.x;
    const int tid = threadIdx.x;
    const size_t base = (size_t)g * PG * D;

    for (int r = 0; r < 2; ++r) {
        int j = r * 256 + tid;
        ((float4*)F[0])[j] = ((const float4*)(f + base))[j];
    }
    if (tid < D) svl[tid] = vl[(size_t)g * D + tid];
    if (tid < PG) spw[tid] = pw[g * PG + tid];
    __syncthreads();

    const int c = tid & (D - 1);
    const int grp = tid >> 7;
    float acc[8];
#pragma unroll
    for (int n = 0; n < 8; ++n) acc[n] = 0.0f;

    for (int k4 = 0; k4 < D / 4; ++k4) {
        const int k = k4 * 4;
        float wu[4];
#pragma unroll
        for (int q = 0; q < 4; ++q) wu[q] = fuT[(size_t)(k + q) * D + c];
#pragma unroll
        for (int n = 0; n < 8; ++n) {
            float4 f4 = *(const float4*)&F[grp * 8 + n][k];
            float ff[4] = {f4.x, f4.y, f4.z, f4.w};
#pragma unroll
            for (int q = 0; q < 4; ++q) acc[n] = fmaf(wu[q], ff[q], acc[n]);
        }
    }

    const float fe = few[c];
    const float vlc = svl[c];
    float p[8];
#pragma unroll
    for (int n = 0; n < 8; ++n) p[n] = sigmoidf_(acc[n] + vlc) * fe;
#pragma unroll
    for (int n = 0; n < 8; ++n)
        for (int off = 32; off; off >>= 1) p[n] += __shfl_xor(p[n], off);
    const int wave = tid >> 6;
    if ((tid & 63) == 0) {
#pragma unroll
        for (int n = 0; n < 8; ++n) epart[wave][n] = p[n];
    }
    __syncthreads();

    if (tid < PG) {
        const int gg = tid >> 3, n = tid & 7;
        float e = epart[gg * 2][n] + epart[gg * 2 + 1][n];
        float mx = e;
#pragma unroll
        for (int off = 8; off; off >>= 1) mx = fmaxf(mx, __shfl_xor(mx, off, 16));
        float ex = __expf(e - mx);
        float s = ex;
#pragma unroll
        for (int off = 8; off; off >>= 1) s += __shfl_xor(s, off, 16);
        alpha[tid] = ex / s;
    }
    __syncthreads();

    float ra = 0.0f, pacc = 0.0f;
#pragma unroll
    for (int n = 0; n < 8; ++n) {
        const int node = grp * 8 + n;
        float fv = F[node][c];
        ra   = fmaf(alpha[node], fv, ra);
        pacc = fmaf(spw[node],  fv, pacc);
    }
    rpart[grp][c] = ra;
    ppart[grp][c] = pacc;
    __syncthreads();
    if (grp == 0) {
        out[(size_t)g * D + c] = rpart[0][c] + rpart[1][c];
        out[(size_t)Bn * D + (size_t)g * D + c] = ppart[0][c] + ppart[1][c];
    }
}

// -------------------------------------------------------------------------
extern "C" void kernel_launch(void* const* d_in, const int* in_sizes, int n_in,
                              void* d_out, int out_size, void* d_ws, size_t ws_size,
                              hipStream_t stream) {
    const float* feat   = (const float*)d_in[0];
    const float* intend = (const float*)d_in[1];
    const float* posw   = (const float*)d_in[2];
    const float* bn1g   = (const float*)d_in[3];
    const float* bn1b   = (const float*)d_in[4];
    const float* bn1m   = (const float*)d_in[5];
    const float* bn1v   = (const float*)d_in[6];
    const float* gwih   = (const float*)d_in[7];
    const float* gwhh   = (const float*)d_in[8];
    const float* gbih   = (const float*)d_in[9];
    const float* gbhh   = (const float*)d_in[10];
    const float* fcs    = (const float*)d_in[11];
    const float* fcn    = (const float*)d_in[12];
    const float* prelu  = (const float*)d_in[13];
    const float* bn2g   = (const float*)d_in[14];
    const float* bn2b   = (const float*)d_in[15];
    const float* bn2m   = (const float*)d_in[16];
    const float* bn2v   = (const float*)d_in[17];
    const float* fcu    = (const float*)d_in[18];
    const float* fcv    = (const float*)d_in[19];
    const float* fcvb   = (const float*)d_in[20];
    const float* fci    = (const float*)d_in[21];
    const float* fcib   = (const float*)d_in[22];
    const float* fce    = (const float*)d_in[23];
    const int* last_nodes = (const int*)d_in[24];
    const int* esrc     = (const int*)d_in[25];
    const int* edst     = (const int*)d_in[26];
    const int* eslot    = (const int*)d_in[27];

    const int N = in_sizes[0] / D;
    const int B = in_sizes[1] / D;
    const int E = in_sizes[25];

    char* wsb = (char*)d_ws;
    char*  x_img  = wsb;                              // N*256 B (bf16 swizzled)
    float* fbuf   = (float*)(x_img + (size_t)N * 256);    // N*D f32
    float* vlb    = fbuf + (size_t)N * D;                 // B*D f32
    float* fuT    = vlb + (size_t)B * D;                  // D*D
    float* fvT    = fuT + D * D;
    float* fiT    = fvT + D * D;
    unsigned short* wih_bf = (unsigned short*)(fiT + D * D);   // 3*D*D bf16
    unsigned short* whh_bf = wih_bf + 3 * D * D;
    unsigned short* fcs_bf = whh_bf + 3 * D * D;               // D*D bf16
    unsigned short* fcn_bf = fcs_bf + D * D;
    float* bn1sc  = (float*)(fcn_bf + D * D);
    float* bn1sh  = bn1sc + D;
    int*   mb     = (int*)(bn1sh + D);                         // N*MAXD ints

    prep_kernel<<<(3 * D * D + 255) / 256, 256, 0, stream>>>(
        gwih, gwhh, fcs, fcn, fcu, fcv, fci,
        bn1g, bn1b, bn1m, bn1v,
        wih_bf, whh_bf, fcs_bf, fcn_bf, fuT, fvT, fiT, bn1sc, bn1sh);
    bn1_kernel<<<(N * 16 + 255) / 256, 256, 0, stream>>>(
        feat, bn1sc, bn1sh, x_img, N * 16);
    mbinit_kernel<<<(N * MAXD + 255) / 256, 256, 0, stream>>>(mb, N * MAXD);
    scatter_kernel<<<(E + 255) / 256, 256, 0, stream>>>(esrc, edst, eslot, mb, E);
    gru_fused_kernel<<<N / 128, 512, 0, stream>>>(
        x_img, mb, wih_bf, whh_bf, gbih, gbhh, fcs_bf, fcn_bf,
        prelu, bn2g, bn2b, bn2m, bn2v, fbuf);
    vl_kernel<<<B / 32, 256, 0, stream>>>(intend, fbuf, last_nodes, fvT, fiT, fcvb, fcib, vlb);
    attn_kernel<<<B, 256, 0, stream>>>(fbuf, vlb, fuT, fce, posw, (float*)d_out, B);
}